// Round 5
// baseline (310.010 us; speedup 1.0000x reference)
//
#include <hip/hip_runtime.h>
#include <hip/hip_cooperative_groups.h>

namespace cg = cooperative_groups;

#define BB 8
#define NN 4096
#define THREADS 512
#define NSPLIT 32
#define CHUNK (NN / NSPLIT)      // 128 DB points per block
#define QPT 8                    // queries per thread (512*8 = 4096 = all queries of one (dir,b))
#define NQ (BB * NN)             // 32768 queries per direction
#define NQ_TOTAL (2 * NQ)        // 65536
#define GRID (2 * BB * NSPLIT)   // 512 blocks = 2 blocks/CU

// bid = dir*256 + b*32 + c ; dir0: db=a1,q=a2 (dist1), dir1: db=a2,q=a1 (dist2)
__global__ __launch_bounds__(THREADS, 4)
void chamfer_fused(const float* __restrict__ a1, const float* __restrict__ a2,
                   float* __restrict__ minpart, float* __restrict__ partials,
                   float* __restrict__ out)
{
    cg::grid_group gg = cg::this_grid();
    __shared__ float4 sdb[CHUNK];
    __shared__ float red[THREADS];

    const int tid = threadIdx.x;
    const int bid = blockIdx.x;

    // ---------------- phase 1: per-chunk min over t' = ||p||^2/2 - p.q ----------------
    {
        const int c   = bid & (NSPLIT - 1);
        const int b   = (bid >> 5) & 7;
        const int dir = bid >> 8;

        const float* dbg = (dir == 0 ? a1 : a2) + (size_t)b * NN * 3;
        const float* qg  = (dir == 0 ? a2 : a1) + (size_t)b * NN * 3;

        // stage CHUNK db points as (x, y, z, ||p||^2 / 2)
        if (tid < CHUNK) {
            const int i = c * CHUNK + tid;
            const float x = dbg[i * 3 + 0];
            const float y = dbg[i * 3 + 1];
            const float z = dbg[i * 3 + 2];
            sdb[tid] = make_float4(x, y, z, 0.5f * fmaf(x, x, fmaf(y, y, z * z)));
        }

        // 8 consecutive queries per thread (24 floats = 6 aligned float4 loads), negated
        float qx[QPT], qy[QPT], qz[QPT];
        {
            const float4* q4 = reinterpret_cast<const float4*>(qg + (size_t)tid * QPT * 3);
            const float4 v0 = q4[0], v1 = q4[1], v2 = q4[2];
            const float4 v3 = q4[3], v4 = q4[4], v5 = q4[5];
            qx[0] = -v0.x; qy[0] = -v0.y; qz[0] = -v0.z;
            qx[1] = -v0.w; qy[1] = -v1.x; qz[1] = -v1.y;
            qx[2] = -v1.z; qy[2] = -v1.w; qz[2] = -v2.x;
            qx[3] = -v2.y; qy[3] = -v2.z; qz[3] = -v2.w;
            qx[4] = -v3.x; qy[4] = -v3.y; qz[4] = -v3.z;
            qx[5] = -v3.w; qy[5] = -v4.x; qz[5] = -v4.y;
            qx[6] = -v4.z; qy[6] = -v4.w; qz[6] = -v5.x;
            qx[7] = -v5.y; qy[7] = -v5.z; qz[7] = -v5.w;
        }

        __syncthreads();

        float m0[QPT], m1[QPT];
        #pragma unroll
        for (int k = 0; k < QPT; ++k) { m0[k] = 3.4e38f; m1[k] = 3.4e38f; }

        // software-pipelined: prefetch next pair while computing current pair.
        // NOTE: no lambdas / by-reference array params here — R4 showed that
        // demotes the arrays to scratch (VGPR_Count=32, 9x slowdown).
        float4 c0 = sdb[0], c1 = sdb[1];
        for (int i = 0; i < CHUNK - 2; i += 2) {
            const float4 n0 = sdb[i + 2];
            const float4 n1 = sdb[i + 3];
            #pragma unroll
            for (int k = 0; k < QPT; ++k) {
                const float t0 = fmaf(c0.x, qx[k], fmaf(c0.y, qy[k], fmaf(c0.z, qz[k], c0.w)));
                const float t1 = fmaf(c1.x, qx[k], fmaf(c1.y, qy[k], fmaf(c1.z, qz[k], c1.w)));
                m0[k] = fminf(m0[k], t0);
                m1[k] = fminf(m1[k], t1);
            }
            c0 = n0; c1 = n1;
        }
        #pragma unroll
        for (int k = 0; k < QPT; ++k) {
            const float t0 = fmaf(c0.x, qx[k], fmaf(c0.y, qy[k], fmaf(c0.z, qz[k], c0.w)));
            const float t1 = fmaf(c1.x, qx[k], fmaf(c1.y, qy[k], fmaf(c1.z, qz[k], c1.w)));
            m0[k] = fminf(m0[k], t0);
            m1[k] = fminf(m1[k], t1);
        }

        float4 o0, o1;
        o0.x = fminf(m0[0], m1[0]); o0.y = fminf(m0[1], m1[1]);
        o0.z = fminf(m0[2], m1[2]); o0.w = fminf(m0[3], m1[3]);
        o1.x = fminf(m0[4], m1[4]); o1.y = fminf(m0[5], m1[5]);
        o1.z = fminf(m0[6], m1[6]); o1.w = fminf(m0[7], m1[7]);

        const size_t qglob = (size_t)dir * NQ + (size_t)b * NN + (size_t)tid * QPT;
        float4* dst = reinterpret_cast<float4*>(minpart + (size_t)c * NQ_TOTAL + qglob);
        dst[0] = o0;
        dst[1] = o1;
    }

    __threadfence();
    gg.sync();

    // ---------------- phase 2: combine NSPLIT slots, add ||q||^2, block partial sum ----
    {
        float d = 0.0f;
        if (tid < 128) {
            const int gq  = bid * 128 + tid;
            const int dir = gq >> 15;
            const int b   = (gq >> 12) & 7;
            const int q   = gq & (NN - 1);

            float mn = 3.4e38f;
            #pragma unroll
            for (int cc = 0; cc < NSPLIT; ++cc)
                mn = fminf(mn, minpart[(size_t)cc * NQ_TOTAL + gq]);

            const float* qp = (dir == 0 ? a2 : a1) + ((size_t)b * NN + q) * 3;
            const float qx = qp[0], qy = qp[1], qz = qp[2];
            const float qn = fmaf(qx, qx, fmaf(qy, qy, qz * qz));
            d = fmaf(2.0f, mn, qn);   // ||p-q||^2 = 2*t' + ||q||^2
        }
        red[tid] = d;
        __syncthreads();
        #pragma unroll
        for (int s = THREADS / 2; s > 0; s >>= 1) {
            if (tid < s) red[tid] += red[tid + s];
            __syncthreads();
        }
        if (tid == 0) partials[bid] = red[0];
    }

    __threadfence();
    gg.sync();

    // ---------------- phase 3: block 0 reduces 512 partials (dir0: 0..255, dir1: 256..511)
    if (bid == 0) {
        red[tid] = partials[tid];
        __syncthreads();
        #pragma unroll
        for (int s = 128; s > 0; s >>= 1) {
            if ((tid & 255) < s) red[tid] += red[tid + s];
            __syncthreads();
        }
        if (tid == 0) {
            const float inv = 1.0f / (float)(BB * NN);
            const float d1 = red[0]   * inv;
            const float d2 = red[256] * inv;
            out[0] = d1 + d2;
            out[1] = d1;
            out[2] = d2;
        }
    }
}

extern "C" void kernel_launch(void* const* d_in, const int* in_sizes, int n_in,
                              void* d_out, int out_size, void* d_ws, size_t ws_size,
                              hipStream_t stream)
{
    const float* a1 = (const float*)d_in[0];
    const float* a2 = (const float*)d_in[1];
    float* out = (float*)d_out;

    float* minpart  = (float*)d_ws;                                   // 32*65536*4 = 8 MB
    float* partials = (float*)((char*)d_ws + (size_t)NSPLIT * NQ_TOTAL * sizeof(float));

    void* args[] = { (void*)&a1, (void*)&a2, (void*)&minpart, (void*)&partials, (void*)&out };
    hipLaunchCooperativeKernel((void*)chamfer_fused, dim3(GRID), dim3(THREADS),
                               args, 0, stream);
}

// Round 6
// 33.951 us; speedup vs baseline: 9.1310x; 9.1310x over previous
//
#include <hip/hip_runtime.h>

#define BB 8
#define NN 4096
#define THREADS 256
#define NSPLIT 32
#define CHUNK (NN / NSPLIT)     // 128 DB points per block
#define QPT 8                   // queries per thread
#define QPB (THREADS * QPT)     // 2048 queries per block
#define NQ (BB * NN)            // 32768 queries per direction
#define NQ_TOTAL (2 * NQ)       // 65536

// bid = dir*512 + b*64 + qb*32 + c ; dir0: db=a1,q=a2 (dist1), dir1: db=a2,q=a1
__global__ __launch_bounds__(THREADS) void chamfer_min_kernel(
    const float* __restrict__ a1, const float* __restrict__ a2,
    float* __restrict__ minpart)
{
    __shared__ float4 sdb[CHUNK];

    const int tid = threadIdx.x;
    const int bid = blockIdx.x;
    const int c   = bid & (NSPLIT - 1);
    const int qb  = (bid >> 5) & 1;
    const int b   = (bid >> 6) & 7;
    const int dir = bid >> 9;

    const float* dbg = (dir == 0 ? a1 : a2) + (size_t)b * NN * 3;
    const float* qg  = (dir == 0 ? a2 : a1) + (size_t)b * NN * 3;

    // stage CHUNK db points as (x, y, z, ||p||^2 / 2)
    if (tid < CHUNK) {
        const int i = c * CHUNK + tid;
        const float x = dbg[i * 3 + 0];
        const float y = dbg[i * 3 + 1];
        const float z = dbg[i * 3 + 2];
        sdb[tid] = make_float4(x, y, z, 0.5f * fmaf(x, x, fmaf(y, y, z * z)));
    }

    // 8 consecutive queries per thread (24 floats = 6 aligned float4 loads), negated
    float qx[QPT], qy[QPT], qz[QPT];
    {
        const float4* q4 = reinterpret_cast<const float4*>(
            qg + (size_t)(qb * QPB + tid * QPT) * 3);
        const float4 v0 = q4[0], v1 = q4[1], v2 = q4[2];
        const float4 v3 = q4[3], v4 = q4[4], v5 = q4[5];
        qx[0] = -v0.x; qy[0] = -v0.y; qz[0] = -v0.z;
        qx[1] = -v0.w; qy[1] = -v1.x; qz[1] = -v1.y;
        qx[2] = -v1.z; qy[2] = -v1.w; qz[2] = -v2.x;
        qx[3] = -v2.y; qy[3] = -v2.z; qz[3] = -v2.w;
        qx[4] = -v3.x; qy[4] = -v3.y; qz[4] = -v3.z;
        qx[5] = -v3.w; qy[5] = -v4.x; qz[5] = -v4.y;
        qx[6] = -v4.z; qy[6] = -v4.w; qz[6] = -v5.x;
        qx[7] = -v5.y; qy[7] = -v5.z; qz[7] = -v5.w;
    }

    __syncthreads();

    float m[QPT];
    #pragma unroll
    for (int k = 0; k < QPT; ++k) m[k] = 3.4e38f;

    // t' = ||p||^2/2 - p.q ; per 2 points & query: 6 fma + 1 min3 (v_min3_f32 fusion)
    #pragma unroll 2
    for (int i = 0; i < CHUNK; i += 2) {
        const float4 p0 = sdb[i];
        const float4 p1 = sdb[i + 1];
        #pragma unroll
        for (int k = 0; k < QPT; ++k) {
            const float t0 = fmaf(p0.x, qx[k], fmaf(p0.y, qy[k], fmaf(p0.z, qz[k], p0.w)));
            const float t1 = fmaf(p1.x, qx[k], fmaf(p1.y, qy[k], fmaf(p1.z, qz[k], p1.w)));
            m[k] = fminf(fminf(t0, t1), m[k]);
        }
    }

    float4 o0, o1;
    o0.x = m[0]; o0.y = m[1]; o0.z = m[2]; o0.w = m[3];
    o1.x = m[4]; o1.y = m[5]; o1.z = m[6]; o1.w = m[7];

    const size_t qglob = (size_t)dir * NQ + (size_t)b * NN + (size_t)(qb * QPB + tid * QPT);
    float4* dst = reinterpret_cast<float4*>(minpart + (size_t)c * NQ_TOTAL + qglob);
    dst[0] = o0;
    dst[1] = o1;
}

// combine the NSPLIT partial mins per query, add ||q||^2, block-sum
__global__ __launch_bounds__(THREADS) void decode_sum_kernel(
    const float* __restrict__ a1, const float* __restrict__ a2,
    const float* __restrict__ minpart, float* __restrict__ partials)
{
    __shared__ float red[THREADS];
    const int tid = threadIdx.x;
    const int bid = blockIdx.x;
    const int gq  = bid * THREADS + tid;
    const int dir = gq >> 15;
    const int b   = (gq >> 12) & 7;
    const int q   = gq & (NN - 1);

    float mn = 3.4e38f;
    #pragma unroll
    for (int cc = 0; cc < NSPLIT; ++cc)
        mn = fminf(mn, minpart[(size_t)cc * NQ_TOTAL + gq]);

    const float* qp = (dir == 0 ? a2 : a1) + ((size_t)b * NN + q) * 3;
    const float qx = qp[0], qy = qp[1], qz = qp[2];
    const float qn = fmaf(qx, qx, fmaf(qy, qy, qz * qz));
    const float d  = fmaf(2.0f, mn, qn);   // ||p-q||^2 = 2*t' + ||q||^2

    red[tid] = d;
    __syncthreads();
    #pragma unroll
    for (int s = THREADS / 2; s > 0; s >>= 1) {
        if (tid < s) red[tid] += red[tid + s];
        __syncthreads();
    }
    if (tid == 0) partials[bid] = red[0];
}

__global__ __launch_bounds__(256) void finalize_kernel(
    const float* __restrict__ partials, float* __restrict__ out)
{
    __shared__ float red[256];
    const int t = threadIdx.x;
    red[t] = partials[t];
    __syncthreads();
    #pragma unroll
    for (int s = 64; s > 0; s >>= 1) {
        if ((t & 127) < s) red[t] += red[t + s];
        __syncthreads();
    }
    if (t == 0) {
        const float inv = 1.0f / (float)(BB * NN);
        const float d1 = red[0]   * inv;   // dir0
        const float d2 = red[128] * inv;   // dir1
        out[0] = d1 + d2;
        out[1] = d1;
        out[2] = d2;
    }
}

extern "C" void kernel_launch(void* const* d_in, const int* in_sizes, int n_in,
                              void* d_out, int out_size, void* d_ws, size_t ws_size,
                              hipStream_t stream)
{
    const float* a1 = (const float*)d_in[0];
    const float* a2 = (const float*)d_in[1];
    float* out = (float*)d_out;

    float* minpart  = (float*)d_ws;   // 32*65536*4 = 8 MB
    float* partials = (float*)((char*)d_ws + (size_t)NSPLIT * NQ_TOTAL * sizeof(float));

    hipLaunchKernelGGL(chamfer_min_kernel, dim3(2 * BB * 2 * NSPLIT), dim3(THREADS), 0, stream,
                       a1, a2, minpart);
    hipLaunchKernelGGL(decode_sum_kernel, dim3(NQ_TOTAL / THREADS), dim3(THREADS), 0, stream,
                       a1, a2, minpart, partials);
    hipLaunchKernelGGL(finalize_kernel, dim3(1), dim3(256), 0, stream,
                       partials, out);
}